// Round 1
// 438.047 us; speedup vs baseline: 1.0190x; 1.0190x over previous
//
#include <hip/hip_runtime.h>
#include <hip/hip_bf16.h>
#include <stdint.h>

#define TLEN 2048
#define CDIM 2048
#define BDIM 2
#define HDIM 16
#define DHEAD 128
// Q/K now packed at stride 2*CDIM; V goes to a separate transposed buffer.
#define QROW ((size_t)(2 * CDIM))

typedef __bf16 bf16x8 __attribute__((ext_vector_type(8)));
typedef float f32x4 __attribute__((ext_vector_type(4)));

__device__ __forceinline__ uint16_t f32_to_bf16(float f) {
    uint32_t u = __builtin_bit_cast(uint32_t, f);
    uint32_t r = (u + 0x7FFFu + ((u >> 16) & 1u)) >> 16;
    return (uint16_t)r;
}
__device__ __forceinline__ float bf16_to_f32(uint32_t h) {
    uint32_t u = h << 16;
    return __builtin_bit_cast(float, u);
}

// async global->LDS, 16B per lane. LDS dest = wave-uniform base + lane*16;
// global source address is per-lane (gather) — used for swizzled staging.
__device__ __forceinline__ void gload_lds16(const uint16_t* g, uint16_t* l) {
    __builtin_amdgcn_global_load_lds(
        (const __attribute__((address_space(1))) uint32_t*)g,
        (__attribute__((address_space(3))) uint32_t*)l, 16, 0, 0);
}

// ---------------- elementwise f32 -> bf16 ----------------
__global__ void cvt_f32_bf16(const float* __restrict__ in, uint16_t* __restrict__ out, int n) {
    int i = (blockIdx.x * blockDim.x + threadIdx.x) * 4;
    if (i + 3 < n) {
        float4 f = *reinterpret_cast<const float4*>(in + i);
        ushort4 o;
        o.x = f32_to_bf16(f.x);
        o.y = f32_to_bf16(f.y);
        o.z = f32_to_bf16(f.z);
        o.w = f32_to_bf16(f.w);
        *reinterpret_cast<ushort4*>(out + i) = o;
    }
}

// ---------------- transpose + cast: in [R][Cc] f32 -> out [Cc][R] bf16 ----------------
__global__ __launch_bounds__(256) void transpose_cvt(const float* __restrict__ in,
                                                     uint16_t* __restrict__ out,
                                                     int R, int Cc) {
    __shared__ uint16_t tile[64][65];
    int c0 = blockIdx.x * 64;
    int r0 = blockIdx.y * 64;
    int tc = threadIdx.x & 63;
    int t4 = threadIdx.x >> 6;  // 0..3
    for (int rr = t4; rr < 64; rr += 4) {
        tile[rr][tc] = f32_to_bf16(in[(size_t)(r0 + rr) * Cc + c0 + tc]);
    }
    __syncthreads();
    int wr = threadIdx.x & 63;
    for (int cc = t4; cc < 64; cc += 4) {
        out[(size_t)(c0 + cc) * R + r0 + wr] = tile[wr][cc];
    }
}

// ================= 256x256 8-phase bf16 MFMA GEMM (m201-style) =================
// C[M][N] = A[M][K] * Bt[N][K]^T. 512 thr = 8 waves (2M x 4N); wave tile 128x64
// (8x4 16x16 frags); BK=64; LDS 128 KiB = 2 bufs x (As 32 KiB + Bs 32 KiB).
// Per K-tile: 4 phases {ds_read subtile || stage 1 half-tile (2x gload_lds w16)
// || barrier; lgkmcnt(0); setprio(1); 16 MFMA; setprio(0); barrier}.
// Counted s_waitcnt vmcnt(4) ONCE per K-tile (never 0 in steady state).
// LDS swizzle: 16B-block c' = c ^ (row&7), realized by pre-swizzling the
// GLOBAL source (gload_lds writes linearly) and XOR-ing on the ds_read side.
// Stage schedule (tile t, phases c1..c4): c1: B-half1(t+1), c2: A-half1(t+1),
// c3: B-half0(t+2), c4: A-half0(t+2) — each write lands >=1 barrier after the
// last read of its region.
// MODE 0: f32 out. MODE 2: QKV split — Q/K cols -> packed bf16 [M][2*CDIM],
// V cols -> transposed bf16 Vt[(b*16+h)*128+d][t].

#define RD8(P, OFF) (*reinterpret_cast<const bf16x8*>((P) + (OFF)))

#define PH_RDA(CA, MB)                                        \
    _Pragma("unroll") for (int mi = 0; mi < 4; mi++) {        \
        af[mi][0] = RD8(CA, rdA + ((MB) + mi) * 1024 + kblk0); \
        af[mi][1] = RD8(CA, rdA + ((MB) + mi) * 1024 + kblk1); \
    }

#define PH_RDB(CB, NIB)                                              \
    _Pragma("unroll") for (int ni = 0; ni < 2; ni++) {               \
        bf[(NIB) + ni][0] = RD8(CB, rdB + ((NIB) + ni) * 1024 + kblk0); \
        bf[(NIB) + ni][1] = RD8(CB, rdB + ((NIB) + ni) * 1024 + kblk1); \
    }

#define PH_MFMA(MB, NIB)                                                        \
    __builtin_amdgcn_s_barrier();                                               \
    asm volatile("s_waitcnt lgkmcnt(0)" ::: "memory");                          \
    __builtin_amdgcn_s_setprio(1);                                              \
    _Pragma("unroll") for (int mi = 0; mi < 4; mi++)                            \
    _Pragma("unroll") for (int ni = 0; ni < 2; ni++) {                          \
        acc[(MB) + mi][(NIB) + ni] = __builtin_amdgcn_mfma_f32_16x16x32_bf16(   \
            af[mi][0], bf[(NIB) + ni][0], acc[(MB) + mi][(NIB) + ni], 0, 0, 0); \
        acc[(MB) + mi][(NIB) + ni] = __builtin_amdgcn_mfma_f32_16x16x32_bf16(   \
            af[mi][1], bf[(NIB) + ni][1], acc[(MB) + mi][(NIB) + ni], 0, 0, 0); \
    }                                                                           \
    __builtin_amdgcn_s_setprio(0);                                              \
    __builtin_amdgcn_s_barrier();                                               \
    __builtin_amdgcn_sched_barrier(0);

#define TILE(T, CA, CB, NA, NB)                              \
    {                                                        \
        const int k0 = (T) * 64;                             \
        PH_RDA(CA, 0)                                        \
        PH_RDB(CB, 0)                                        \
        if ((T) + 1 < nt) stB(NB, 1, k0 + 64);               \
        PH_MFMA(0, 0)                                        \
        PH_RDB(CB, 2)                                        \
        if ((T) + 1 < nt) stA(NA, 1, k0 + 64);               \
        PH_MFMA(0, 2)                                        \
        PH_RDA(CA, 4)                                        \
        if ((T) + 2 < nt) stB(CB, 0, k0 + 128);              \
        PH_MFMA(4, 2)                                        \
        if ((T) + 2 < nt) {                                  \
            stA(CA, 0, k0 + 128);                            \
            asm volatile("s_waitcnt vmcnt(4)" ::: "memory"); \
        } else if ((T) + 1 < nt) {                           \
            asm volatile("s_waitcnt vmcnt(0)" ::: "memory"); \
        }                                                    \
        PH_MFMA(4, 0)                                        \
    }

template <int MODE>
__global__ __launch_bounds__(512, 2) void gemm_bf16_256(const uint16_t* __restrict__ A,
                                                        const uint16_t* __restrict__ Bt,
                                                        void* __restrict__ Cp,
                                                        uint16_t* __restrict__ vt,
                                                        int M, int N, int K) {
    __shared__ __align__(16) uint16_t lds[65536];  // 128 KiB
    uint16_t* const As0 = lds;
    uint16_t* const Bs0 = lds + 16384;
    uint16_t* const As1 = lds + 32768;
    uint16_t* const Bs1 = lds + 49152;

    const int tid = threadIdx.x;
    const int wave = tid >> 6;
    const int lane = tid & 63;
    const int l15 = lane & 15;
    const int quad = lane >> 4;
    const int wrow = wave >> 2;  // 0..1
    const int wcol = wave & 3;   // 0..3

    // bijective XCD swizzle (nwg % 8 == 0 for both call sites)
    const int gx = gridDim.x;
    const int nwg = gx * gridDim.y;
    const int flat = blockIdx.y * gx + blockIdx.x;
    const int cpx = nwg >> 3;
    const int id2 = (flat & 7) * cpx + (flat >> 3);
    const int n0 = (id2 % gx) * 256;
    const int m0 = (id2 / gx) * 256;

    // staging: lane -> row (lane>>3) within 8-row slab, source 16B-block
    // (lane&7) ^ (lane>>3) so that LDS (r, c') holds global block c' ^ (r&7).
    const int srow = wave * 8 + (lane >> 3);
    const int scol = ((lane & 7) ^ (lane >> 3)) * 8;
    const uint16_t* Ag = A + (size_t)(m0 + srow) * K + scol;
    const uint16_t* Bg = Bt + (size_t)(n0 + srow) * K + scol;
    const int ldsoff = wave * 512;

    // frag-read constants: row = strip + frag*16 + l15 (row&7 == l15&7)
    const int rdA = (wrow * 128 + l15) * 64;
    const int rdB = (wcol * 64 + l15) * 64;
    const int kblk0 = (quad ^ (l15 & 7)) * 8;
    const int kblk1 = ((4 + quad) ^ (l15 & 7)) * 8;

    const int nt = K >> 6;
    f32x4 acc[8][4] = {};
    bf16x8 af[4][2], bf[4][2];

    auto stA = [&](uint16_t* dstb, int hf, int kk) {
        const uint16_t* s = Ag + (size_t)(hf * 128) * K + kk;
        uint16_t* d = dstb + hf * 8192 + ldsoff;
        gload_lds16(s, d);
        gload_lds16(s + (size_t)64 * K, d + 4096);
    };
    auto stB = [&](uint16_t* dstb, int hf, int kk) {
        const uint16_t* s = Bg + (size_t)(hf * 128) * K + kk;
        uint16_t* d = dstb + hf * 8192 + ldsoff;
        gload_lds16(s, d);
        gload_lds16(s + (size_t)64 * K, d + 4096);
    };

    // prologue: steady-state issue order [B0(0),A0(0),B1(0),A1(0),B0(1),A0(1)]
    stB(Bs0, 0, 0);
    stA(As0, 0, 0);
    stB(Bs0, 1, 0);
    stA(As0, 1, 0);
    stB(Bs1, 0, 64);
    stA(As1, 0, 64);
    asm volatile("s_waitcnt vmcnt(4)" ::: "memory");
    __builtin_amdgcn_s_barrier();
    __builtin_amdgcn_sched_barrier(0);

    for (int t = 0; t < nt; t += 2) {
        TILE(t, As0, Bs0, As1, Bs1)
        TILE(t + 1, As1, Bs1, As0, Bs0)
    }

    const bool vmode = (MODE == 2) && (n0 >= 2 * CDIM);  // block-uniform
#pragma unroll
    for (int mi = 0; mi < 8; mi++)
#pragma unroll
        for (int ni = 0; ni < 4; ni++) {
            if (vmode) {
                // V cols: write transposed into Vt[(b*16+h)*128+d][t].
                int col = n0 + wcol * 64 + ni * 16 + l15;
                int vcol = col - 2 * CDIM;
                int hh = vcol >> 7, d = vcol & 127;
                int rowm = m0 + wrow * 128 + mi * 16 + quad * 4;
                int bb = rowm >> 11, tt = rowm & 2047;
                uint32_t lo = (uint32_t)f32_to_bf16(acc[mi][ni][0]) |
                              ((uint32_t)f32_to_bf16(acc[mi][ni][1]) << 16);
                uint32_t hi = (uint32_t)f32_to_bf16(acc[mi][ni][2]) |
                              ((uint32_t)f32_to_bf16(acc[mi][ni][3]) << 16);
                *reinterpret_cast<uint2*>(
                    vt + ((size_t)((bb * HDIM + hh) * DHEAD + d)) * TLEN + tt) =
                    make_uint2(lo, hi);
            } else {
#pragma unroll
                for (int r = 0; r < 4; r++) {
                    int row = m0 + wrow * 128 + mi * 16 + quad * 4 + r;
                    int col = n0 + wcol * 64 + ni * 16 + l15;
                    float v = acc[mi][ni][r];
                    if (MODE == 2)
                        ((uint16_t*)Cp)[(size_t)row * (2 * CDIM) + col] = f32_to_bf16(v);
                    else if (MODE == 1)
                        ((uint16_t*)Cp)[(size_t)row * N + col] = f32_to_bf16(v);
                    else
                        ((float*)Cp)[(size_t)row * N + col] = v;
                }
            }
        }
}

// ---------------- 128x128 m97-style GEMM (kept for the proj GEMM) ----------------
template <int MODE>
__global__ __launch_bounds__(256) void gemm_bf16_128(const uint16_t* __restrict__ A,
                                                     const uint16_t* __restrict__ Bt,
                                                     void* __restrict__ Cp,
                                                     uint16_t* __restrict__ vt,
                                                     int M, int N, int K) {
    __shared__ __align__(16) uint16_t As[128 * 32];
    __shared__ __align__(16) uint16_t Bs[128 * 32];
    const int tid = threadIdx.x;
    const int wave = tid >> 6;
    const int lane = tid & 63;
    const int l15 = lane & 15;
    const int quad = lane >> 4;
    const int m0 = blockIdx.y * 128;
    const int n0 = blockIdx.x * 128;
    const int wm = (wave >> 1) * 64;
    const int wn = (wave & 1) * 64;

    f32x4 acc[4][4] = {};

    const int s0 = wave * 2;
    const int lrow = lane >> 2;
    const int swzW = (lrow ^ (lrow >> 2)) & 3;
    const int cblk = (lane & 3) ^ swzW;
    const uint16_t* Ag = A + (size_t)(m0 + s0 * 16 + lrow) * K + cblk * 8;
    const uint16_t* Bg = Bt + (size_t)(n0 + s0 * 16 + lrow) * K + cblk * 8;
    uint16_t* AsW0 = As + s0 * 512;
    uint16_t* AsW1 = As + (s0 + 1) * 512;
    uint16_t* BsW0 = Bs + s0 * 512;
    uint16_t* BsW1 = Bs + (s0 + 1) * 512;
    const size_t rowStep = (size_t)16 * K;

    const int swzR = (l15 ^ (l15 >> 2)) & 3;
    const int rdblk = (quad ^ swzR) * 8;

    for (int k0 = 0; k0 < K; k0 += 32) {
        gload_lds16(Ag + k0, AsW0);
        gload_lds16(Ag + rowStep + k0, AsW1);
        gload_lds16(Bg + k0, BsW0);
        gload_lds16(Bg + rowStep + k0, BsW1);
        __syncthreads();

        bf16x8 af[4], bfr[4];
#pragma unroll
        for (int mi = 0; mi < 4; mi++)
            af[mi] = *reinterpret_cast<const bf16x8*>(
                As + (wm + mi * 16 + l15) * 32 + rdblk);
#pragma unroll
        for (int ni = 0; ni < 4; ni++)
            bfr[ni] = *reinterpret_cast<const bf16x8*>(
                Bs + (wn + ni * 16 + l15) * 32 + rdblk);
#pragma unroll
        for (int mi = 0; mi < 4; mi++)
#pragma unroll
            for (int ni = 0; ni < 4; ni++)
                acc[mi][ni] = __builtin_amdgcn_mfma_f32_16x16x32_bf16(
                    af[mi], bfr[ni], acc[mi][ni], 0, 0, 0);
        __syncthreads();
    }

#pragma unroll
    for (int mi = 0; mi < 4; mi++)
#pragma unroll
        for (int ni = 0; ni < 4; ni++) {
#pragma unroll
            for (int r = 0; r < 4; r++) {
                int row = m0 + wm + mi * 16 + quad * 4 + r;
                int col = n0 + wn + ni * 16 + l15;
                float v = acc[mi][ni][r];
                if (MODE != 0)
                    ((uint16_t*)Cp)[(size_t)row * N + col] = f32_to_bf16(v);
                else
                    ((float*)Cp)[(size_t)row * N + col] = v;
            }
        }
}

// ---------------- MFMA flash attention v3 (QROW now 2*CDIM) ----------------
#define ATT_C1 0.12751743f
#define ATT_C2 17.3123405f

__global__ __launch_bounds__(256) void attn_mfma3(const uint16_t* __restrict__ qkv,
                                                  const uint16_t* __restrict__ vtg,
                                                  uint16_t* __restrict__ y) {
    __shared__ __align__(16) uint16_t Ks[64 * 128];    // swizzled: c' = c ^ (key&15)
    __shared__ __align__(16) uint16_t Vts[128 * 64];   // swizzled: c' = c ^ (d&7)
    __shared__ __align__(16) uint16_t Ps[4][32 * 72];  // per-wave P [q][key]

    const int tid = threadIdx.x;
    const int wave = tid >> 6;
    const int lane = tid & 63;
    const int l15 = lane & 15;
    const int quad = lane >> 4;
    const int h = blockIdx.y;
    const int b = blockIdx.z;
    const int qblk = (int)gridDim.x - 1 - (int)blockIdx.x;
    const int qbase = qblk * 128 + wave * 32;
    const int kmax = qbase + 31;

    const uint16_t* kg = qkv + (size_t)b * TLEN * QROW + CDIM + h * DHEAD;
    const uint16_t* vg = vtg + (size_t)(b * HDIM + h) * DHEAD * TLEN;
    uint16_t* PsW = Ps[wave];

    int koff[4], voff[4];
#pragma unroll
    for (int i = 0; i < 4; i++) {
        int Lb = (wave * 4 + i) * 64 + lane;
        int key = Lb >> 4;
        int ck = (Lb & 15) ^ (key & 15);
        koff[i] = key * (int)QROW + ck * 8;
        int d = Lb >> 3;
        int cv = (Lb & 7) ^ (d & 7);
        voff[i] = d * TLEN + cv * 8;
    }

    bf16x8 qfrag[2][4];
#pragma unroll
    for (int m = 0; m < 2; m++) {
        const uint16_t* qp =
            qkv + (size_t)(b * TLEN + qbase + m * 16 + l15) * QROW + h * DHEAD + quad * 8;
#pragma unroll
        for (int kc = 0; kc < 4; kc++)
            qfrag[m][kc] = *reinterpret_cast<const bf16x8*>(qp + kc * 32);
    }

    f32x4 oacc[2][8] = {};
    float psum[2] = {0.f, 0.f};

    const int diagT = qblk * 2 + (wave >> 1);
    const int ntiles = qblk * 2 + 2;

    for (int t = 0; t < ntiles; t++) {
        const int j0 = t * 64;
        if (t > 0) __syncthreads();
        {
            const uint16_t* kj = kg + (size_t)j0 * QROW;
            const uint16_t* vj = vg + j0;
#pragma unroll
            for (int i = 0; i < 4; i++) {
                gload_lds16(kj + koff[i], Ks + (wave * 4 + i) * 512);
                gload_lds16(vj + voff[i], Vts + (wave * 4 + i) * 512);
            }
        }
        __syncthreads();
        if (t > diagT) continue;

        const bool masked = (t == diagT);
        const int n0max = masked ? ((kmax - j0) >> 4) : 3;

        f32x4 st[4][2];
#pragma unroll
        for (int n0 = 0; n0 < 4; n0++) {
            if (masked && n0 > n0max) continue;
            bf16x8 kf[4];
#pragma unroll
            for (int kc = 0; kc < 4; kc++) {
                int cpr = (kc * 4 + quad) ^ l15;
                kf[kc] = *reinterpret_cast<const bf16x8*>(
                    Ks + (n0 * 16 + l15) * 128 + cpr * 8);
            }
#pragma unroll
            for (int m = 0; m < 2; m++) {
                f32x4 acc = {};
#pragma unroll
                for (int kc = 0; kc < 4; kc++)
                    acc = __builtin_amdgcn_mfma_f32_16x16x32_bf16(
                        kf[kc], qfrag[m][kc], acc, 0, 0, 0);
                st[n0][m] = acc;
            }
        }

#pragma unroll
        for (int n0 = 0; n0 < 4; n0++) {
            if (masked && n0 > n0max) continue;
#pragma unroll
            for (int m = 0; m < 2; m++) {
                uint32_t pk0, pk1;
                float pv[4];
#pragma unroll
                for (int r = 0; r < 4; r++) {
                    float p = exp2f(st[n0][m][r] * ATT_C1 - ATT_C2);
                    if (masked) {
                        int key = j0 + n0 * 16 + quad * 4 + r;
                        int q = qbase + m * 16 + l15;
                        if (key > q) p = 0.f;
                    }
                    uint32_t pb = f32_to_bf16(p);
                    pv[r] = bf16_to_f32(pb);
                    if (r == 0) pk0 = pb;
                    else if (r == 1) pk0 |= pb << 16;
                    else if (r == 2) pk1 = pb;
                    else pk1 |= pb << 16;
                }
                psum[m] += (pv[0] + pv[1]) + (pv[2] + pv[3]);
                *reinterpret_cast<uint2*>(PsW + (m * 16 + l15) * 72 + n0 * 16 + quad * 4) =
                    make_uint2(pk0, pk1);
            }
        }

        const int kcend = masked ? (((kmax - j0) >> 5) + 1) : 2;
#pragma unroll
        for (int kc = 0; kc < 2; kc++) {
            if (kc >= kcend) continue;
            bf16x8 pf[2];
#pragma unroll
            for (int m = 0; m < 2; m++)
                pf[m] = *reinterpret_cast<const bf16x8*>(
                    PsW + (m * 16 + l15) * 72 + kc * 32 + quad * 8);
#pragma unroll
            for (int n0 = 0; n0 < 8; n0++) {
                int cpr = (kc * 4 + quad) ^ (l15 & 7);
                bf16x8 vf = *reinterpret_cast<const bf16x8*>(
                    Vts + (n0 * 16 + l15) * 64 + cpr * 8);
#pragma unroll
                for (int m = 0; m < 2; m++)
                    oacc[m][n0] = __builtin_amdgcn_mfma_f32_16x16x32_bf16(
                        pf[m], vf, oacc[m][n0], 0, 0, 0);
            }
        }
    }

#pragma unroll
    for (int m = 0; m < 2; m++) {
        float s = psum[m];
        s += __shfl_xor(s, 16);
        s += __shfl_xor(s, 32);
        psum[m] = 1.0f / s;
    }
    uint16_t* ybase = y + (size_t)(b * TLEN + qbase) * CDIM + h * DHEAD;
#pragma unroll
    for (int m = 0; m < 2; m++)
#pragma unroll
        for (int r = 0; r < 4; r++) {
            float inv = __shfl(psum[m], quad * 4 + r);
#pragma unroll
            for (int n0 = 0; n0 < 8; n0++)
                ybase[(size_t)(m * 16 + quad * 4 + r) * CDIM + n0 * 16 + l15] =
                    f32_to_bf16(oacc[m][n0][r] * inv);
        }
}

extern "C" void kernel_launch(void* const* d_in, const int* in_sizes, int n_in,
                              void* d_out, int out_size, void* d_ws, size_t ws_size,
                              hipStream_t stream) {
    const float* x = (const float*)d_in[0];       // [2,2048,2048]
    const float* w_attn = (const float*)d_in[1];  // [2048, 6144]
    const float* w_proj = (const float*)d_in[2];  // [2048, 2048]
    float* out = (float*)d_out;                   // [2,2048,2048]

    const int M = BDIM * TLEN;  // 4096
    const int K = CDIM;         // 2048
    const int N3 = 3 * CDIM;    // 6144

    char* ws = (char*)d_ws;
    uint16_t* xb = (uint16_t*)(ws);               // 16 MB: x bf16 (A of GEMM1; NOT aliased anymore)
    uint16_t* waT = (uint16_t*)(ws + 16777216);   // 24 MB: w_attn^T bf16 [6144][2048]
    uint16_t* wpT = (uint16_t*)(ws + 41943040);   // 8 MB: w_proj^T bf16 [2048][2048]
    uint16_t* qkp = (uint16_t*)(ws + 50331648);   // 32 MB: packed Q/K bf16 [4096][4096]
    uint16_t* vtb = (uint16_t*)(ws + 83886080);   // 16 MB: Vt bf16 [(b*16+h)*128+d][2048]
    uint16_t* yb = (uint16_t*)(ws + 100663296);   // 16 MB: y bf16 [4096][2048]

    // 1. cast x to bf16
    cvt_f32_bf16<<<(M * K / 4 + 255) / 256, 256, 0, stream>>>(x, xb, M * K);
    // 2. transpose+cast weights
    transpose_cvt<<<dim3(N3 / 64, K / 64), 256, 0, stream>>>(w_attn, waT, K, N3);
    transpose_cvt<<<dim3(K / 64, K / 64), 256, 0, stream>>>(w_proj, wpT, K, K);
    // 3. qkv = x @ w_attn; Q/K cols -> qkp (stride 4096), V cols -> vtb transposed
    gemm_bf16_256<2><<<dim3(N3 / 256, M / 256), 512, 0, stream>>>(xb, waT, (void*)qkp, vtb, M, N3, K);
    // 4. attention -> y bf16 [4096][2048]
    attn_mfma3<<<dim3(TLEN / 128, HDIM, BDIM), 256, 0, stream>>>(qkp, vtb, yb);
    // 5. out = y @ w_proj   fp32 [4096][2048]
    gemm_bf16_128<0><<<dim3(K / 128, M / 128), 256, 0, stream>>>(yb, wpT, (void*)out, nullptr, M, K, K);
}

// Round 3
// 434.499 us; speedup vs baseline: 1.0273x; 1.0082x over previous
//
#include <hip/hip_runtime.h>
#include <hip/hip_bf16.h>
#include <stdint.h>

#define TLEN 2048
#define CDIM 2048
#define BDIM 2
#define HDIM 16
#define DHEAD 128
// Q/K packed at stride 2*CDIM; V goes to a separate transposed buffer.
#define QROW ((size_t)(2 * CDIM))

typedef __bf16 bf16x8 __attribute__((ext_vector_type(8)));
typedef float f32x4 __attribute__((ext_vector_type(4)));

__device__ __forceinline__ uint16_t f32_to_bf16(float f) {
    uint32_t u = __builtin_bit_cast(uint32_t, f);
    uint32_t r = (u + 0x7FFFu + ((u >> 16) & 1u)) >> 16;
    return (uint16_t)r;
}
__device__ __forceinline__ float bf16_to_f32(uint32_t h) {
    uint32_t u = h << 16;
    return __builtin_bit_cast(float, u);
}

// async global->LDS, 16B per lane. LDS dest = wave-uniform base + lane*16;
// global source address is per-lane (gather) — used for swizzled staging.
__device__ __forceinline__ void gload_lds16(const uint16_t* g, uint16_t* l) {
    __builtin_amdgcn_global_load_lds(
        (const __attribute__((address_space(1))) uint32_t*)g,
        (__attribute__((address_space(3))) uint32_t*)l, 16, 0, 0);
}

// ---------------- elementwise f32 -> bf16 ----------------
__global__ void cvt_f32_bf16(const float* __restrict__ in, uint16_t* __restrict__ out, int n) {
    int i = (blockIdx.x * blockDim.x + threadIdx.x) * 4;
    if (i + 3 < n) {
        float4 f = *reinterpret_cast<const float4*>(in + i);
        ushort4 o;
        o.x = f32_to_bf16(f.x);
        o.y = f32_to_bf16(f.y);
        o.z = f32_to_bf16(f.z);
        o.w = f32_to_bf16(f.w);
        *reinterpret_cast<ushort4*>(out + i) = o;
    }
}

// ---------------- transpose + cast: in [R][Cc] f32 -> out [Cc][R] bf16 ----------------
__global__ __launch_bounds__(256) void transpose_cvt(const float* __restrict__ in,
                                                     uint16_t* __restrict__ out,
                                                     int R, int Cc) {
    __shared__ uint16_t tile[64][65];
    int c0 = blockIdx.x * 64;
    int r0 = blockIdx.y * 64;
    int tc = threadIdx.x & 63;
    int t4 = threadIdx.x >> 6;  // 0..3
    for (int rr = t4; rr < 64; rr += 4) {
        tile[rr][tc] = f32_to_bf16(in[(size_t)(r0 + rr) * Cc + c0 + tc]);
    }
    __syncthreads();
    int wr = threadIdx.x & 63;
    for (int cc = t4; cc < 64; cc += 4) {
        out[(size_t)(c0 + cc) * R + r0 + wr] = tile[wr][cc];
    }
}

// ============ 256x256 8-phase bf16 MFMA GEMM with half-unit LDS ring ============
// C[M][N] = A[M][K] * Bt[N][K]^T. 512 thr = 8 waves (2M x 4N); wave tile 128x64
// (8x4 16x16 frags); BK=64.
// LDS = per-operand RING of 4 half-unit slots (unit = 128 rows x 64 K = 16 KiB).
// Unit (t,h) [h = row-half] lives in slot (2t+h)&3: even tiles read slots 0/1,
// odd tiles 2/3 — static in the 2-tile-unrolled loop.
// Slot lifetime: B slots are last ds_read in phase c2, A slots in c3 (all waves,
// enforced by that phase's closing barrier). So tile t stages tile t+2's B units
// in c3 and A units in c4 — stage->use distance 5-6 phases (~2 tiles), and the
// per-tile s_waitcnt vmcnt(8) only waits on loads issued one full tile earlier
// (tile t-1's 8 loads), leaving tile t's 8 loads in flight across the boundary.
// LDS swizzle: 16B-block c' = c ^ (row&7), realized by pre-swizzling the GLOBAL
// source (gload_lds writes linearly) and XOR-ing on the ds_read side. Within a
// half-unit, frag row & 7 == l15 & 7 and stage row & 7 == lane>>3.
// MODE 0: f32 out. MODE 2: QKV split — Q/K cols -> packed bf16 [M][2*CDIM],
// V cols -> transposed bf16 Vt[(b*16+h)*128+d][t].

#define RD8(P, OFF) (*reinterpret_cast<const bf16x8*>((P) + (OFF)))

#define PH_RDA(BA, MB)                                              \
    _Pragma("unroll") for (int mi = 0; mi < 4; mi++) {              \
        af[mi][0] = RD8(BA, rdAo + ((MB) + mi) * 1024 + kblk0);     \
        af[mi][1] = RD8(BA, rdAo + ((MB) + mi) * 1024 + kblk1);     \
    }

#define PH_RDB(BB, NIB)                                                  \
    _Pragma("unroll") for (int ni = 0; ni < 2; ni++) {                   \
        bf[(NIB) + ni][0] = RD8(BB, rdBo + ((NIB) + ni) * 1024 + kblk0); \
        bf[(NIB) + ni][1] = RD8(BB, rdBo + ((NIB) + ni) * 1024 + kblk1); \
    }

#define PH_MFMA(MB, NIB)                                                        \
    __builtin_amdgcn_s_barrier();                                               \
    asm volatile("s_waitcnt lgkmcnt(0)" ::: "memory");                          \
    __builtin_amdgcn_s_setprio(1);                                              \
    _Pragma("unroll") for (int mi = 0; mi < 4; mi++)                            \
    _Pragma("unroll") for (int ni = 0; ni < 2; ni++) {                          \
        acc[(MB) + mi][(NIB) + ni] = __builtin_amdgcn_mfma_f32_16x16x32_bf16(   \
            af[mi][0], bf[(NIB) + ni][0], acc[(MB) + mi][(NIB) + ni], 0, 0, 0); \
        acc[(MB) + mi][(NIB) + ni] = __builtin_amdgcn_mfma_f32_16x16x32_bf16(   \
            af[mi][1], bf[(NIB) + ni][1], acc[(MB) + mi][(NIB) + ni], 0, 0, 0); \
    }                                                                           \
    __builtin_amdgcn_s_setprio(0);                                              \
    __builtin_amdgcn_s_barrier();                                               \
    __builtin_amdgcn_sched_barrier(0);

// Phases: c1 = reads(A 0-3, B 0-1) + MFMA(0,0); c2 = reads(B 2-3) + MFMA(0,2);
// c3 = reads(A 4-7) + stage B(t+2) + MFMA(4,2); c4 = stage A(t+2) + vmcnt + MFMA(4,0).
#define TILE(S, T)                                           \
    {                                                        \
        const int k0 = (T) * 64;                             \
        const uint16_t* bA = As + ((S) + wrow) * 8192;       \
        const uint16_t* bB = Bs + ((S) + bsel) * 8192;       \
        PH_RDA(bA, 0)                                        \
        PH_RDB(bB, 0)                                        \
        PH_MFMA(0, 0)                                        \
        PH_RDB(bB, 2)                                        \
        PH_MFMA(0, 2)                                        \
        PH_RDA(bA, 4)                                        \
        if ((T) + 2 < nt) {                                  \
            stB((S), 0, k0 + 128);                           \
            stB((S), 1, k0 + 128);                           \
        }                                                    \
        PH_MFMA(4, 2)                                        \
        if ((T) + 2 < nt) {                                  \
            stA((S), 0, k0 + 128);                           \
            stA((S), 1, k0 + 128);                           \
            asm volatile("s_waitcnt vmcnt(8)" ::: "memory"); \
        } else {                                             \
            asm volatile("s_waitcnt vmcnt(0)" ::: "memory"); \
        }                                                    \
        PH_MFMA(4, 0)                                        \
    }

template <int MODE>
__global__ __launch_bounds__(512, 2) void gemm_bf16_256(const uint16_t* __restrict__ A,
                                                        const uint16_t* __restrict__ Bt,
                                                        void* __restrict__ Cp,
                                                        uint16_t* __restrict__ vt,
                                                        int M, int N, int K) {
    __shared__ __align__(16) uint16_t lds[65536];  // 128 KiB
    uint16_t* const As = lds;          // 4 ring slots x 8192 elems (128 rows x 64 K)
    uint16_t* const Bs = lds + 32768;  // 4 ring slots

    const int tid = threadIdx.x;
    const int wave = tid >> 6;
    const int lane = tid & 63;
    const int l15 = lane & 15;
    const int quad = lane >> 4;
    const int wrow = wave >> 2;  // 0..1 -> A half
    const int wcol = wave & 3;   // 0..3
    const int bsel = wcol >> 1;  // B half

    // bijective XCD swizzle (nwg % 8 == 0 for both call sites)
    const int gx = gridDim.x;
    const int nwg = gx * gridDim.y;
    const int flat = blockIdx.y * gx + blockIdx.x;
    const int cpx = nwg >> 3;
    const int id2 = (flat & 7) * cpx + (flat >> 3);
    const int n0 = (id2 % gx) * 256;
    const int m0 = (id2 / gx) * 256;

    // staging: lane -> row (lane>>3) within 8-row slab, source 16B-block
    // (lane&7) ^ (lane>>3) so that LDS (r, c') holds global block c' ^ (r&7).
    const int srow = wave * 8 + (lane >> 3);
    const int scol = ((lane & 7) ^ (lane >> 3)) * 8;
    const uint16_t* Ag = A + (size_t)(m0 + srow) * K + scol;
    const uint16_t* Bg = Bt + (size_t)(n0 + srow) * K + scol;
    const int ldsoff = wave * 512;

    // frag-read constants within a half-unit (row&7 == l15&7 for all frag rows)
    const int rdAo = l15 * 64;
    const int rdBo = ((wcol & 1) * 64 + l15) * 64;
    const int kblk0 = (quad ^ (l15 & 7)) * 8;
    const int kblk1 = ((4 + quad) ^ (l15 & 7)) * 8;

    const int nt = K >> 6;
    f32x4 acc[8][4] = {};
    bf16x8 af[4][2], bf[4][2];

    auto stA = [&](int sb, int h, int kk) {
        const uint16_t* s = Ag + (size_t)(h * 128) * K + kk;
        uint16_t* d = As + (sb + h) * 8192 + ldsoff;
        gload_lds16(s, d);
        gload_lds16(s + (size_t)64 * K, d + 4096);
    };
    auto stB = [&](int sb, int h, int kk) {
        const uint16_t* s = Bg + (size_t)(h * 128) * K + kk;
        uint16_t* d = Bs + (sb + h) * 8192 + ldsoff;
        gload_lds16(s, d);
        gload_lds16(s + (size_t)64 * K, d + 4096);
    };

    // prologue: tile 0 -> slots 0/1, tile 1 -> slots 2/3 (16 loads);
    // vmcnt(8) = tile-0 units complete, tile-1 units stay in flight.
    stB(0, 0, 0);
    stB(0, 1, 0);
    stA(0, 0, 0);
    stA(0, 1, 0);
    stB(2, 0, 64);
    stB(2, 1, 64);
    stA(2, 0, 64);
    stA(2, 1, 64);
    asm volatile("s_waitcnt vmcnt(8)" ::: "memory");
    __builtin_amdgcn_s_barrier();
    __builtin_amdgcn_sched_barrier(0);

    for (int t = 0; t < nt; t += 2) {
        TILE(0, t)
        TILE(2, t + 1)
    }

    const bool vmode = (MODE == 2) && (n0 >= 2 * CDIM);  // block-uniform
#pragma unroll
    for (int mi = 0; mi < 8; mi++)
#pragma unroll
        for (int ni = 0; ni < 4; ni++) {
            if (vmode) {
                // V cols: write transposed into Vt[(b*16+h)*128+d][t].
                int col = n0 + wcol * 64 + ni * 16 + l15;
                int vcol = col - 2 * CDIM;
                int hh = vcol >> 7, d = vcol & 127;
                int rowm = m0 + wrow * 128 + mi * 16 + quad * 4;
                int bb = rowm >> 11, tt = rowm & 2047;
                uint32_t lo = (uint32_t)f32_to_bf16(acc[mi][ni][0]) |
                              ((uint32_t)f32_to_bf16(acc[mi][ni][1]) << 16);
                uint32_t hi = (uint32_t)f32_to_bf16(acc[mi][ni][2]) |
                              ((uint32_t)f32_to_bf16(acc[mi][ni][3]) << 16);
                *reinterpret_cast<uint2*>(
                    vt + ((size_t)((bb * HDIM + hh) * DHEAD + d)) * TLEN + tt) =
                    make_uint2(lo, hi);
            } else {
#pragma unroll
                for (int r = 0; r < 4; r++) {
                    int row = m0 + wrow * 128 + mi * 16 + quad * 4 + r;
                    int col = n0 + wcol * 64 + ni * 16 + l15;
                    float v = acc[mi][ni][r];
                    if (MODE == 2)
                        ((uint16_t*)Cp)[(size_t)row * (2 * CDIM) + col] = f32_to_bf16(v);
                    else if (MODE == 1)
                        ((uint16_t*)Cp)[(size_t)row * N + col] = f32_to_bf16(v);
                    else
                        ((float*)Cp)[(size_t)row * N + col] = v;
                }
            }
        }
}

// ---------------- MFMA flash attention v3 (QROW = 2*CDIM) ----------------
#define ATT_C1 0.12751743f
#define ATT_C2 17.3123405f

__global__ __launch_bounds__(256) void attn_mfma3(const uint16_t* __restrict__ qkv,
                                                  const uint16_t* __restrict__ vtg,
                                                  uint16_t* __restrict__ y) {
    __shared__ __align__(16) uint16_t Ks[64 * 128];    // swizzled: c' = c ^ (key&15)
    __shared__ __align__(16) uint16_t Vts[128 * 64];   // swizzled: c' = c ^ (d&7)
    __shared__ __align__(16) uint16_t Ps[4][32 * 72];  // per-wave P [q][key]

    const int tid = threadIdx.x;
    const int wave = tid >> 6;
    const int lane = tid & 63;
    const int l15 = lane & 15;
    const int quad = lane >> 4;
    const int h = blockIdx.y;
    const int b = blockIdx.z;
    const int qblk = (int)gridDim.x - 1 - (int)blockIdx.x;
    const int qbase = qblk * 128 + wave * 32;
    const int kmax = qbase + 31;

    const uint16_t* kg = qkv + (size_t)b * TLEN * QROW + CDIM + h * DHEAD;
    const uint16_t* vg = vtg + (size_t)(b * HDIM + h) * DHEAD * TLEN;
    uint16_t* PsW = Ps[wave];

    int koff[4], voff[4];
#pragma unroll
    for (int i = 0; i < 4; i++) {
        int Lb = (wave * 4 + i) * 64 + lane;
        int key = Lb >> 4;
        int ck = (Lb & 15) ^ (key & 15);
        koff[i] = key * (int)QROW + ck * 8;
        int d = Lb >> 3;
        int cv = (Lb & 7) ^ (d & 7);
        voff[i] = d * TLEN + cv * 8;
    }

    bf16x8 qfrag[2][4];
#pragma unroll
    for (int m = 0; m < 2; m++) {
        const uint16_t* qp =
            qkv + (size_t)(b * TLEN + qbase + m * 16 + l15) * QROW + h * DHEAD + quad * 8;
#pragma unroll
        for (int kc = 0; kc < 4; kc++)
            qfrag[m][kc] = *reinterpret_cast<const bf16x8*>(qp + kc * 32);
    }

    f32x4 oacc[2][8] = {};
    float psum[2] = {0.f, 0.f};

    const int diagT = qblk * 2 + (wave >> 1);
    const int ntiles = qblk * 2 + 2;

    for (int t = 0; t < ntiles; t++) {
        const int j0 = t * 64;
        if (t > 0) __syncthreads();
        {
            const uint16_t* kj = kg + (size_t)j0 * QROW;
            const uint16_t* vj = vg + j0;
#pragma unroll
            for (int i = 0; i < 4; i++) {
                gload_lds16(kj + koff[i], Ks + (wave * 4 + i) * 512);
                gload_lds16(vj + voff[i], Vts + (wave * 4 + i) * 512);
            }
        }
        __syncthreads();
        if (t > diagT) continue;

        const bool masked = (t == diagT);
        const int n0max = masked ? ((kmax - j0) >> 4) : 3;

        f32x4 st[4][2];
#pragma unroll
        for (int n0 = 0; n0 < 4; n0++) {
            if (masked && n0 > n0max) continue;
            bf16x8 kf[4];
#pragma unroll
            for (int kc = 0; kc < 4; kc++) {
                int cpr = (kc * 4 + quad) ^ l15;
                kf[kc] = *reinterpret_cast<const bf16x8*>(
                    Ks + (n0 * 16 + l15) * 128 + cpr * 8);
            }
#pragma unroll
            for (int m = 0; m < 2; m++) {
                f32x4 acc = {};
#pragma unroll
                for (int kc = 0; kc < 4; kc++)
                    acc = __builtin_amdgcn_mfma_f32_16x16x32_bf16(
                        kf[kc], qfrag[m][kc], acc, 0, 0, 0);
                st[n0][m] = acc;
            }
        }

#pragma unroll
        for (int n0 = 0; n0 < 4; n0++) {
            if (masked && n0 > n0max) continue;
#pragma unroll
            for (int m = 0; m < 2; m++) {
                uint32_t pk0, pk1;
                float pv[4];
#pragma unroll
                for (int r = 0; r < 4; r++) {
                    float p = exp2f(st[n0][m][r] * ATT_C1 - ATT_C2);
                    if (masked) {
                        int key = j0 + n0 * 16 + quad * 4 + r;
                        int q = qbase + m * 16 + l15;
                        if (key > q) p = 0.f;
                    }
                    uint32_t pb = f32_to_bf16(p);
                    pv[r] = bf16_to_f32(pb);
                    if (r == 0) pk0 = pb;
                    else if (r == 1) pk0 |= pb << 16;
                    else if (r == 2) pk1 = pb;
                    else pk1 |= pb << 16;
                }
                psum[m] += (pv[0] + pv[1]) + (pv[2] + pv[3]);
                *reinterpret_cast<uint2*>(PsW + (m * 16 + l15) * 72 + n0 * 16 + quad * 4) =
                    make_uint2(pk0, pk1);
            }
        }

        const int kcend = masked ? (((kmax - j0) >> 5) + 1) : 2;
#pragma unroll
        for (int kc = 0; kc < 2; kc++) {
            if (kc >= kcend) continue;
            bf16x8 pf[2];
#pragma unroll
            for (int m = 0; m < 2; m++)
                pf[m] = *reinterpret_cast<const bf16x8*>(
                    PsW + (m * 16 + l15) * 72 + kc * 32 + quad * 8);
#pragma unroll
            for (int n0 = 0; n0 < 8; n0++) {
                int cpr = (kc * 4 + quad) ^ (l15 & 7);
                bf16x8 vf = *reinterpret_cast<const bf16x8*>(
                    Vts + (n0 * 16 + l15) * 64 + cpr * 8);
#pragma unroll
                for (int m = 0; m < 2; m++)
                    oacc[m][n0] = __builtin_amdgcn_mfma_f32_16x16x32_bf16(
                        pf[m], vf, oacc[m][n0], 0, 0, 0);
            }
        }
    }

#pragma unroll
    for (int m = 0; m < 2; m++) {
        float s = psum[m];
        s += __shfl_xor(s, 16);
        s += __shfl_xor(s, 32);
        psum[m] = 1.0f / s;
    }
    uint16_t* ybase = y + (size_t)(b * TLEN + qbase) * CDIM + h * DHEAD;
#pragma unroll
    for (int m = 0; m < 2; m++)
#pragma unroll
        for (int r = 0; r < 4; r++) {
            float inv = __shfl(psum[m], quad * 4 + r);
#pragma unroll
            for (int n0 = 0; n0 < 8; n0++)
                ybase[(size_t)(m * 16 + quad * 4 + r) * CDIM + n0 * 16 + l15] =
                    f32_to_bf16(oacc[m][n0][r] * inv);
        }
}

extern "C" void kernel_launch(void* const* d_in, const int* in_sizes, int n_in,
                              void* d_out, int out_size, void* d_ws, size_t ws_size,
                              hipStream_t stream) {
    const float* x = (const float*)d_in[0];       // [2,2048,2048]
    const float* w_attn = (const float*)d_in[1];  // [2048, 6144]
    const float* w_proj = (const float*)d_in[2];  // [2048, 2048]
    float* out = (float*)d_out;                   // [2,2048,2048]

    const int M = BDIM * TLEN;  // 4096
    const int K = CDIM;         // 2048
    const int N3 = 3 * CDIM;    // 6144

    char* ws = (char*)d_ws;
    uint16_t* xb = (uint16_t*)(ws);               // 16 MB: x bf16
    uint16_t* waT = (uint16_t*)(ws + 16777216);   // 24 MB: w_attn^T bf16 [6144][2048]
    uint16_t* wpT = (uint16_t*)(ws + 41943040);   // 8 MB: w_proj^T bf16 [2048][2048]
    uint16_t* qkp = (uint16_t*)(ws + 50331648);   // 32 MB: packed Q/K bf16 [4096][4096]
    uint16_t* vtb = (uint16_t*)(ws + 83886080);   // 16 MB: Vt bf16 [(b*16+h)*128+d][2048]
    uint16_t* yb = (uint16_t*)(ws + 100663296);   // 16 MB: y bf16 [4096][2048]

    // 1. cast x to bf16
    cvt_f32_bf16<<<(M * K / 4 + 255) / 256, 256, 0, stream>>>(x, xb, M * K);
    // 2. transpose+cast weights
    transpose_cvt<<<dim3(N3 / 64, K / 64), 256, 0, stream>>>(w_attn, waT, K, N3);
    transpose_cvt<<<dim3(K / 64, K / 64), 256, 0, stream>>>(w_proj, wpT, K, K);
    // 3. qkv = x @ w_attn; Q/K cols -> qkp (stride 4096), V cols -> vtb transposed
    gemm_bf16_256<2><<<dim3(N3 / 256, M / 256), 512, 0, stream>>>(xb, waT, (void*)qkp, vtb, M, N3, K);
    // 4. attention -> y bf16 [4096][2048]
    attn_mfma3<<<dim3(TLEN / 128, HDIM, BDIM), 256, 0, stream>>>(qkp, vtb, yb);
    // 5. out = y @ w_proj   fp32 [4096][2048]
    gemm_bf16_256<0><<<dim3(K / 256, M / 256), 512, 0, stream>>>(yb, wpT, (void*)out, nullptr, M, K, K);
}